// Round 3
// baseline (9883.625 us; speedup 1.0000x reference)
//
#include <hip/hip_runtime.h>

#define Bsz 2048
#define Ssz 96
#define Fsz 32
#define Hsz 256
#define Osz 6
#define LAsz 32
#define RT 8                  // batch rows per block; grid = 256 blocks = 1/CU
#define NSTEP (Ssz + LAsz)
#define NTHR 512              // 8 waves: 2 row-halves x 256 channels

// ---------- accurate f64 exp (|rel err| ~1e-14) ----------
__device__ __forceinline__ double exp_d(double x) {
    x = fmin(fmax(x, -700.0), 700.0);
    const double LOG2E = 1.4426950408889634074;
    const double LN2HI = 6.93147180369123816490e-01;
    const double LN2LO = 1.90821492927058770002e-10;
    double n = __builtin_rint(x * LOG2E);
    double r = fma(-n, LN2HI, x);
    r = fma(-n, LN2LO, r);
    double p = 2.5052108385441718775e-08;
    p = fma(p, r, 2.7557319223985890653e-07);
    p = fma(p, r, 2.7557319223985892511e-06);
    p = fma(p, r, 2.4801587301587301566e-05);
    p = fma(p, r, 1.9841269841269841253e-04);
    p = fma(p, r, 1.3888888888888889419e-03);
    p = fma(p, r, 8.3333333333333332177e-03);
    p = fma(p, r, 4.1666666666666664354e-02);
    p = fma(p, r, 1.6666666666666665741e-01);
    p = fma(p, r, 5.0e-01);
    p = fma(p, r, 1.0);
    p = fma(p, r, 1.0);
    long long bits = (long long)(1023 + (int)n) << 52;
    return p * __longlong_as_double(bits);
}
__device__ __forceinline__ double sigmoid_d(double x) { return 1.0 / (1.0 + exp_d(-x)); }
__device__ __forceinline__ double tanh_d(double x) {
    double ax = fabs(x);
    double t = exp_d(-2.0 * ax);
    double r = (1.0 - t) / (1.0 + t);
    return x >= 0.0 ? r : -r;
}

// 8 ascending-k FMAs into one accumulator (order matches round-2 kernel)
#define DOT8(accv, WA, WB)                              \
    accv = fma((double)WA.x, h01.x, accv);              \
    accv = fma((double)WA.y, h01.y, accv);              \
    accv = fma((double)WA.z, h23.x, accv);              \
    accv = fma((double)WA.w, h23.y, accv);              \
    accv = fma((double)WB.x, h45.x, accv);              \
    accv = fma((double)WB.y, h45.y, accv);              \
    accv = fma((double)WB.z, h67.x, accv);              \
    accv = fma((double)WB.w, h67.y, accv);

__global__ __launch_bounds__(NTHR, 2) void lstm_persist(
    const float* __restrict__ x, const float* __restrict__ W_ih,
    const float* __restrict__ W_hh, const float* __restrict__ b_ih,
    const float* __restrict__ b_hh, const float* __restrict__ W_fc,
    const float* __restrict__ b_fc, float* __restrict__ out)
{
    __shared__ __align__(16) double h_lds[RT][Hsz];     // 16 KB
    __shared__ __align__(16) double x_lds[RT][Fsz];     // 2 KB
    __shared__ double o_lds[RT][Osz];
    __shared__ float  wfc_lds[Osz * Hsz];               // 6 KB

    const int tid  = threadIdx.x;
    const int row0 = blockIdx.x * RT;
    const int j    = tid & (Hsz - 1);                    // channel
    const int r0   = (tid >> 8) * 4;                     // row half: rows r0..r0+3

    for (int i = tid; i < RT * Hsz; i += NTHR) ((double*)h_lds)[i] = 0.0;
    for (int i = tid; i < Osz * Hsz; i += NTHR) wfc_lds[i] = W_fc[i];

    const float* wih0 = W_ih + (size_t)(0 * Hsz + j) * Fsz;
    const float* wih1 = W_ih + (size_t)(1 * Hsz + j) * Fsz;
    const float* wih2 = W_ih + (size_t)(2 * Hsz + j) * Fsz;
    const float* wih3 = W_ih + (size_t)(3 * Hsz + j) * Fsz;
    const float* whh0 = W_hh + (size_t)(0 * Hsz + j) * Hsz;
    const float* whh1 = W_hh + (size_t)(1 * Hsz + j) * Hsz;
    const float* whh2 = W_hh + (size_t)(2 * Hsz + j) * Hsz;
    const float* whh3 = W_hh + (size_t)(3 * Hsz + j) * Hsz;

    const double bias0 = (double)b_ih[0 * Hsz + j] + (double)b_hh[0 * Hsz + j];
    const double bias1 = (double)b_ih[1 * Hsz + j] + (double)b_hh[1 * Hsz + j];
    const double bias2 = (double)b_ih[2 * Hsz + j] + (double)b_hh[2 * Hsz + j];
    const double bias3 = (double)b_ih[3 * Hsz + j] + (double)b_hh[3 * Hsz + j];

    double c_reg[4];
    #pragma unroll
    for (int r = 0; r < 4; ++r) c_reg[r] = 0.0;

    __syncthreads();

    for (int t = 0; t < NSTEP; ++t) {
        // ---- stage x[:, t (or t-Ssz), :]; fuse look-ahead o replacement ----
        if (tid < RT * Fsz) {
            int r = tid >> 5, f = tid & 31;
            int ts = (t < Ssz) ? t : (t - Ssz);
            double v;
            if (t >= Ssz && f < Osz) v = o_lds[r][f];
            else v = (double)x[((size_t)(row0 + r) * Ssz + ts) * Fsz + f];
            x_lds[r][f] = v;
        }
        __syncthreads();

        double acc[4][4];
        #pragma unroll
        for (int r = 0; r < 4; ++r) {
            acc[0][r] = bias0; acc[1][r] = bias1; acc[2][r] = bias2; acc[3][r] = bias3;
        }

        // ---- F part: gates += W_ih . x ----
        #pragma unroll 1
        for (int k0 = 0; k0 < Fsz; k0 += 8) {
            float4 wa[4], wb[4];
            wa[0] = *(const float4*)(wih0 + k0); wb[0] = *(const float4*)(wih0 + k0 + 4);
            wa[1] = *(const float4*)(wih1 + k0); wb[1] = *(const float4*)(wih1 + k0 + 4);
            wa[2] = *(const float4*)(wih2 + k0); wb[2] = *(const float4*)(wih2 + k0 + 4);
            wa[3] = *(const float4*)(wih3 + k0); wb[3] = *(const float4*)(wih3 + k0 + 4);
            #pragma unroll
            for (int r = 0; r < 4; ++r) {
                double2 h01 = *(const double2*)&x_lds[r0 + r][k0];
                double2 h23 = *(const double2*)&x_lds[r0 + r][k0 + 2];
                double2 h45 = *(const double2*)&x_lds[r0 + r][k0 + 4];
                double2 h67 = *(const double2*)&x_lds[r0 + r][k0 + 6];
                DOT8(acc[0][r], wa[0], wb[0]);
                DOT8(acc[1][r], wa[1], wb[1]);
                DOT8(acc[2][r], wa[2], wb[2]);
                DOT8(acc[3][r], wa[3], wb[3]);
            }
        }

        // ---- H part: gates += W_hh . h  (next-chunk weight prefetch) ----
        {
            float4 wa[4], wb[4], na[4], nb[4];
            wa[0] = *(const float4*)(whh0); wb[0] = *(const float4*)(whh0 + 4);
            wa[1] = *(const float4*)(whh1); wb[1] = *(const float4*)(whh1 + 4);
            wa[2] = *(const float4*)(whh2); wb[2] = *(const float4*)(whh2 + 4);
            wa[3] = *(const float4*)(whh3); wb[3] = *(const float4*)(whh3 + 4);
            #pragma unroll 1
            for (int k0 = 0; k0 < Hsz; k0 += 8) {
                int kn = (k0 + 8 < Hsz) ? (k0 + 8) : 0;
                na[0] = *(const float4*)(whh0 + kn); nb[0] = *(const float4*)(whh0 + kn + 4);
                na[1] = *(const float4*)(whh1 + kn); nb[1] = *(const float4*)(whh1 + kn + 4);
                na[2] = *(const float4*)(whh2 + kn); nb[2] = *(const float4*)(whh2 + kn + 4);
                na[3] = *(const float4*)(whh3 + kn); nb[3] = *(const float4*)(whh3 + kn + 4);
                #pragma unroll
                for (int r = 0; r < 4; ++r) {
                    double2 h01 = *(const double2*)&h_lds[r0 + r][k0];
                    double2 h23 = *(const double2*)&h_lds[r0 + r][k0 + 2];
                    double2 h45 = *(const double2*)&h_lds[r0 + r][k0 + 4];
                    double2 h67 = *(const double2*)&h_lds[r0 + r][k0 + 6];
                    DOT8(acc[0][r], wa[0], wb[0]);
                    DOT8(acc[1][r], wa[1], wb[1]);
                    DOT8(acc[2][r], wa[2], wb[2]);
                    DOT8(acc[3][r], wa[3], wb[3]);
                }
                #pragma unroll
                for (int g = 0; g < 4; ++g) { wa[g] = na[g]; wb[g] = nb[g]; }
            }
        }

        __syncthreads();   // all h_lds/x_lds reads complete before h update

        // ---- activations; update c (regs) and h (LDS) ----
        #pragma unroll
        for (int r = 0; r < 4; ++r) {
            double si = sigmoid_d(acc[0][r]);
            double sf = sigmoid_d(acc[1][r]);
            double tg = tanh_d(acc[2][r]);
            double so = sigmoid_d(acc[3][r]);
            double cn = fma(sf, c_reg[r], si * tg);
            c_reg[r] = cn;
            h_lds[r0 + r][j] = so * tanh_d(cn);
        }

        // ---- readout (post-warm-up and every LA step): wave w owns row w ----
        if (t >= Ssz - 1) {
            __syncthreads();                              // h_lds complete
            const int w    = tid >> 6;                    // row
            const int lane = tid & 63;
            double a0 = 0.0, a1 = 0.0, a2 = 0.0, a3 = 0.0, a4 = 0.0, a5 = 0.0;
            #pragma unroll
            for (int m = 0; m < 4; ++m) {
                int k = lane + 64 * m;
                double hv = h_lds[w][k];
                bool b = hv > 0.0;
                a0 += b ? (double)wfc_lds[0 * Hsz + k] : 0.0;
                a1 += b ? (double)wfc_lds[1 * Hsz + k] : 0.0;
                a2 += b ? (double)wfc_lds[2 * Hsz + k] : 0.0;
                a3 += b ? (double)wfc_lds[3 * Hsz + k] : 0.0;
                a4 += b ? (double)wfc_lds[4 * Hsz + k] : 0.0;
                a5 += b ? (double)wfc_lds[5 * Hsz + k] : 0.0;
            }
            #pragma unroll
            for (int off = 32; off >= 1; off >>= 1) {
                a0 += __shfl_down(a0, off, 64);
                a1 += __shfl_down(a1, off, 64);
                a2 += __shfl_down(a2, off, 64);
                a3 += __shfl_down(a3, off, 64);
                a4 += __shfl_down(a4, off, 64);
                a5 += __shfl_down(a5, off, 64);
            }
            if (lane == 0) {
                size_t base = ((size_t)(row0 + w) * (LAsz + 1) + (t - (Ssz - 1))) * Osz;
                double o;
                o = (double)b_fc[0] + a0; o_lds[w][0] = o; out[base + 0] = (float)o;
                o = (double)b_fc[1] + a1; o_lds[w][1] = o; out[base + 1] = (float)o;
                o = (double)b_fc[2] + a2; o_lds[w][2] = o; out[base + 2] = (float)o;
                o = (double)b_fc[3] + a3; o_lds[w][3] = o; out[base + 3] = (float)o;
                o = (double)b_fc[4] + a4; o_lds[w][4] = o; out[base + 4] = (float)o;
                o = (double)b_fc[5] + a5; o_lds[w][5] = o; out[base + 5] = (float)o;
            }
            __syncthreads();                              // o_lds published
        }
        // non-readout steps: next iteration's stage barrier orders h writes vs reads
    }
}

extern "C" void kernel_launch(void* const* d_in, const int* in_sizes, int n_in,
                              void* d_out, int out_size, void* d_ws, size_t ws_size,
                              hipStream_t stream)
{
    const float* x    = (const float*)d_in[0];
    const float* W_ih = (const float*)d_in[1];
    const float* W_hh = (const float*)d_in[2];
    const float* b_ih = (const float*)d_in[3];
    const float* b_hh = (const float*)d_in[4];
    const float* W_fc = (const float*)d_in[5];
    const float* b_fc = (const float*)d_in[6];
    float* out = (float*)d_out;

    lstm_persist<<<dim3(Bsz / RT), dim3(NTHR), 0, stream>>>(
        x, W_ih, W_hh, b_ih, b_hh, W_fc, b_fc, out);
}

// Round 4
// 4672.277 us; speedup vs baseline: 2.1154x; 2.1154x over previous
//
#include <hip/hip_runtime.h>

#define Bsz 2048
#define Ssz 96
#define Fsz 32
#define Hsz 256
#define Osz 6
#define LAsz 32
#define RT 8                  // batch rows per block; grid = 256 blocks = 1/CU
#define NSTEP (Ssz + LAsz)
#define NTHR 256              // thread = gate-channel j; 8 rows per thread

// ---------- accurate f64 exp (|rel err| ~1e-14) ----------
__device__ __forceinline__ double exp_d(double x) {
    x = fmin(fmax(x, -700.0), 700.0);
    const double LOG2E = 1.4426950408889634074;
    const double LN2HI = 6.93147180369123816490e-01;
    const double LN2LO = 1.90821492927058770002e-10;
    double n = __builtin_rint(x * LOG2E);
    double r = fma(-n, LN2HI, x);
    r = fma(-n, LN2LO, r);
    double p = 2.5052108385441718775e-08;
    p = fma(p, r, 2.7557319223985890653e-07);
    p = fma(p, r, 2.7557319223985892511e-06);
    p = fma(p, r, 2.4801587301587301566e-05);
    p = fma(p, r, 1.9841269841269841253e-04);
    p = fma(p, r, 1.3888888888888889419e-03);
    p = fma(p, r, 8.3333333333333332177e-03);
    p = fma(p, r, 4.1666666666666664354e-02);
    p = fma(p, r, 1.6666666666666665741e-01);
    p = fma(p, r, 5.0e-01);
    p = fma(p, r, 1.0);
    p = fma(p, r, 1.0);
    long long bits = (long long)(1023 + (int)n) << 52;
    return p * __longlong_as_double(bits);
}
__device__ __forceinline__ double sigmoid_d(double x) { return 1.0 / (1.0 + exp_d(-x)); }
__device__ __forceinline__ double tanh_d(double x) {
    double ax = fabs(x);
    double t = exp_d(-2.0 * ax);
    double r = (1.0 - t) / (1.0 + t);
    return x >= 0.0 ? r : -r;
}

// 8 ascending-k FMAs into one accumulator (order matches rounds 1-3)
#define DOT8(accv, WA, WB)                              \
    accv = fma((double)WA.x, h01.x, accv);              \
    accv = fma((double)WA.y, h01.y, accv);              \
    accv = fma((double)WA.z, h23.x, accv);              \
    accv = fma((double)WA.w, h23.y, accv);              \
    accv = fma((double)WB.x, h45.x, accv);              \
    accv = fma((double)WB.y, h45.y, accv);              \
    accv = fma((double)WB.z, h67.x, accv);              \
    accv = fma((double)WB.w, h67.y, accv);

// ---------- pre-pass: transpose weights into k-major float4 tiles ----------
// wihT[k4][gr] = W_ih[gr][4*k4 .. 4*k4+3]   (k4 = 0..7,  gr = 0..1023)
// whhT[k4][gr] = W_hh[gr][4*k4 .. 4*k4+3]   (k4 = 0..63, gr = 0..1023)
__global__ void transpose_w(const float* __restrict__ W_ih,
                            const float* __restrict__ W_hh,
                            float4* __restrict__ wihT,
                            float4* __restrict__ whhT)
{
    int i = blockIdx.x * 256 + threadIdx.x;   // 1024 * 72 total
    if (i >= 1024 * 72) return;
    int gr = i / 72, s = i - gr * 72;
    if (s < 8) {
        const float* p = W_ih + (size_t)gr * Fsz + s * 4;
        wihT[s * 1024 + gr] = make_float4(p[0], p[1], p[2], p[3]);
    } else {
        int k4 = s - 8;
        const float* p = W_hh + (size_t)gr * Hsz + k4 * 4;
        whhT[k4 * 1024 + gr] = make_float4(p[0], p[1], p[2], p[3]);
    }
}

__global__ __launch_bounds__(NTHR, 1) void lstm_persist(
    const float* __restrict__ x,
    const float4* __restrict__ wihT, const float4* __restrict__ whhT,
    const float* __restrict__ b_ih, const float* __restrict__ b_hh,
    const float* __restrict__ W_fc, const float* __restrict__ b_fc,
    float* __restrict__ out)
{
    __shared__ __align__(16) double h_lds[RT][Hsz];     // 16 KB
    __shared__ __align__(16) double x_lds[RT][Fsz];     // 2 KB
    __shared__ double o_lds[RT][Osz];
    __shared__ float  wfc_lds[Osz * Hsz];               // 6 KB

    const int tid  = threadIdx.x;
    const int row0 = blockIdx.x * RT;
    const int j    = tid;                                // gate-channel owned

    for (int i = tid; i < RT * Hsz; i += NTHR) ((double*)h_lds)[i] = 0.0;
    for (int i = tid; i < Osz * Hsz; i += NTHR) wfc_lds[i] = W_fc[i];

    const double bias0 = (double)b_ih[0 * Hsz + j] + (double)b_hh[0 * Hsz + j];
    const double bias1 = (double)b_ih[1 * Hsz + j] + (double)b_hh[1 * Hsz + j];
    const double bias2 = (double)b_ih[2 * Hsz + j] + (double)b_hh[2 * Hsz + j];
    const double bias3 = (double)b_ih[3 * Hsz + j] + (double)b_hh[3 * Hsz + j];

    double c_reg[RT];
    #pragma unroll
    for (int r = 0; r < RT; ++r) c_reg[r] = 0.0;

    __syncthreads();

    for (int t = 0; t < NSTEP; ++t) {
        // ---- stage x[:, t (or t-Ssz), :]; fuse look-ahead o replacement ----
        {
            int r = tid >> 5, f = tid & 31;
            int ts = (t < Ssz) ? t : (t - Ssz);
            double v;
            if (t >= Ssz && f < Osz) v = o_lds[r][f];
            else v = (double)x[((size_t)(row0 + r) * Ssz + ts) * Fsz + f];
            x_lds[r][f] = v;
        }
        __syncthreads();

        double acc[4][RT];
        #pragma unroll
        for (int r = 0; r < RT; ++r) {
            acc[0][r] = bias0; acc[1][r] = bias1; acc[2][r] = bias2; acc[3][r] = bias3;
        }

        // ---- F part: gates += W_ih . x  (coalesced k-major weight loads) ----
        #pragma unroll 1
        for (int k0 = 0; k0 < Fsz; k0 += 8) {
            const int s = k0 >> 2;
            float4 wa[4], wb[4];
            #pragma unroll
            for (int g = 0; g < 4; ++g) {
                wa[g] = wihT[(size_t)s * 1024 + (g << 8) + j];
                wb[g] = wihT[(size_t)(s + 1) * 1024 + (g << 8) + j];
            }
            #pragma unroll
            for (int r = 0; r < RT; ++r) {
                double2 h01 = *(const double2*)&x_lds[r][k0];
                double2 h23 = *(const double2*)&x_lds[r][k0 + 2];
                double2 h45 = *(const double2*)&x_lds[r][k0 + 4];
                double2 h67 = *(const double2*)&x_lds[r][k0 + 6];
                DOT8(acc[0][r], wa[0], wb[0]);
                DOT8(acc[1][r], wa[1], wb[1]);
                DOT8(acc[2][r], wa[2], wb[2]);
                DOT8(acc[3][r], wa[3], wb[3]);
            }
        }

        // ---- H part: gates += W_hh . h  (coalesced, next-chunk prefetch) ----
        {
            float4 wa[4], wb[4], na[4], nb[4];
            #pragma unroll
            for (int g = 0; g < 4; ++g) {
                wa[g] = whhT[(size_t)0 * 1024 + (g << 8) + j];
                wb[g] = whhT[(size_t)1 * 1024 + (g << 8) + j];
            }
            #pragma unroll 1
            for (int k0 = 0; k0 < Hsz; k0 += 8) {
                const int sn = (k0 + 8 < Hsz) ? ((k0 + 8) >> 2) : 0;
                #pragma unroll
                for (int g = 0; g < 4; ++g) {
                    na[g] = whhT[(size_t)sn * 1024 + (g << 8) + j];
                    nb[g] = whhT[(size_t)(sn + 1) * 1024 + (g << 8) + j];
                }
                #pragma unroll
                for (int r = 0; r < RT; ++r) {
                    double2 h01 = *(const double2*)&h_lds[r][k0];
                    double2 h23 = *(const double2*)&h_lds[r][k0 + 2];
                    double2 h45 = *(const double2*)&h_lds[r][k0 + 4];
                    double2 h67 = *(const double2*)&h_lds[r][k0 + 6];
                    DOT8(acc[0][r], wa[0], wb[0]);
                    DOT8(acc[1][r], wa[1], wb[1]);
                    DOT8(acc[2][r], wa[2], wb[2]);
                    DOT8(acc[3][r], wa[3], wb[3]);
                }
                #pragma unroll
                for (int g = 0; g < 4; ++g) { wa[g] = na[g]; wb[g] = nb[g]; }
            }
        }

        __syncthreads();   // all h_lds/x_lds reads complete before h update

        // ---- activations; update c (regs) and h (LDS) ----
        #pragma unroll
        for (int r = 0; r < RT; ++r) {
            double si = sigmoid_d(acc[0][r]);
            double sf = sigmoid_d(acc[1][r]);
            double tg = tanh_d(acc[2][r]);
            double so = sigmoid_d(acc[3][r]);
            double cn = fma(sf, c_reg[r], si * tg);
            c_reg[r] = cn;
            h_lds[r][j] = so * tanh_d(cn);
        }

        // ---- readout: 4 waves x 2 row-halves, width-32 butterfly ----
        if (t >= Ssz - 1) {
            __syncthreads();                              // h_lds complete
            const int w = tid >> 6;                       // wave 0..3
            const int r = w * 2 + ((tid >> 5) & 1);       // row 0..7
            const int s = tid & 31;                       // sublane
            double a0 = 0.0, a1 = 0.0, a2 = 0.0, a3 = 0.0, a4 = 0.0, a5 = 0.0;
            #pragma unroll
            for (int m = 0; m < 8; ++m) {
                int k = s + 32 * m;
                double hv = h_lds[r][k];
                bool b = hv > 0.0;
                a0 += b ? (double)wfc_lds[0 * Hsz + k] : 0.0;
                a1 += b ? (double)wfc_lds[1 * Hsz + k] : 0.0;
                a2 += b ? (double)wfc_lds[2 * Hsz + k] : 0.0;
                a3 += b ? (double)wfc_lds[3 * Hsz + k] : 0.0;
                a4 += b ? (double)wfc_lds[4 * Hsz + k] : 0.0;
                a5 += b ? (double)wfc_lds[5 * Hsz + k] : 0.0;
            }
            #pragma unroll
            for (int off = 16; off >= 1; off >>= 1) {
                a0 += __shfl_down(a0, off, 32);
                a1 += __shfl_down(a1, off, 32);
                a2 += __shfl_down(a2, off, 32);
                a3 += __shfl_down(a3, off, 32);
                a4 += __shfl_down(a4, off, 32);
                a5 += __shfl_down(a5, off, 32);
            }
            if (s == 0) {
                size_t base = ((size_t)(row0 + r) * (LAsz + 1) + (t - (Ssz - 1))) * Osz;
                double o;
                o = (double)b_fc[0] + a0; o_lds[r][0] = o; out[base + 0] = (float)o;
                o = (double)b_fc[1] + a1; o_lds[r][1] = o; out[base + 1] = (float)o;
                o = (double)b_fc[2] + a2; o_lds[r][2] = o; out[base + 2] = (float)o;
                o = (double)b_fc[3] + a3; o_lds[r][3] = o; out[base + 3] = (float)o;
                o = (double)b_fc[4] + a4; o_lds[r][4] = o; out[base + 4] = (float)o;
                o = (double)b_fc[5] + a5; o_lds[r][5] = o; out[base + 5] = (float)o;
            }
            __syncthreads();                              // o_lds published
        }
        // non-readout steps: next iteration's stage barrier orders h writes vs reads
    }
}

extern "C" void kernel_launch(void* const* d_in, const int* in_sizes, int n_in,
                              void* d_out, int out_size, void* d_ws, size_t ws_size,
                              hipStream_t stream)
{
    const float* x    = (const float*)d_in[0];
    const float* W_ih = (const float*)d_in[1];
    const float* W_hh = (const float*)d_in[2];
    const float* b_ih = (const float*)d_in[3];
    const float* b_hh = (const float*)d_in[4];
    const float* W_fc = (const float*)d_in[5];
    const float* b_fc = (const float*)d_in[6];
    float* out = (float*)d_out;

    float4* whhT = (float4*)d_ws;                 // 64*1024 float4 = 1 MB
    float4* wihT = whhT + 64 * 1024;              // 8*1024 float4 = 128 KB

    transpose_w<<<dim3((1024 * 72 + 255) / 256), dim3(256), 0, stream>>>(
        W_ih, W_hh, wihT, whhT);

    lstm_persist<<<dim3(Bsz / RT), dim3(NTHR), 0, stream>>>(
        x, wihT, whhT, b_ih, b_hh, W_fc, b_fc, out);
}

// Round 5
// 4465.152 us; speedup vs baseline: 2.2135x; 1.0464x over previous
//
#include <hip/hip_runtime.h>

#define Bsz 2048
#define Ssz 96
#define Fsz 32
#define Hsz 256
#define Osz 6
#define LAsz 32
#define RT 4                  // batch rows per block; grid = 512 = 2 blocks/CU
#define NSTEP (Ssz + LAsz)
#define NTHR 256              // thread = gate-channel j; RT rows per thread

// ---------- accurate f64 exp (|rel err| ~1e-14) ----------
__device__ __forceinline__ double exp_d(double x) {
    x = fmin(fmax(x, -700.0), 700.0);
    const double LOG2E = 1.4426950408889634074;
    const double LN2HI = 6.93147180369123816490e-01;
    const double LN2LO = 1.90821492927058770002e-10;
    double n = __builtin_rint(x * LOG2E);
    double r = fma(-n, LN2HI, x);
    r = fma(-n, LN2LO, r);
    double p = 2.5052108385441718775e-08;
    p = fma(p, r, 2.7557319223985890653e-07);
    p = fma(p, r, 2.7557319223985892511e-06);
    p = fma(p, r, 2.4801587301587301566e-05);
    p = fma(p, r, 1.9841269841269841253e-04);
    p = fma(p, r, 1.3888888888888889419e-03);
    p = fma(p, r, 8.3333333333333332177e-03);
    p = fma(p, r, 4.1666666666666664354e-02);
    p = fma(p, r, 1.6666666666666665741e-01);
    p = fma(p, r, 5.0e-01);
    p = fma(p, r, 1.0);
    p = fma(p, r, 1.0);
    long long bits = (long long)(1023 + (int)n) << 52;
    return p * __longlong_as_double(bits);
}
__device__ __forceinline__ double sigmoid_d(double x) { return 1.0 / (1.0 + exp_d(-x)); }
__device__ __forceinline__ double tanh_d(double x) {
    double ax = fabs(x);
    double t = exp_d(-2.0 * ax);
    double r = (1.0 - t) / (1.0 + t);
    return x >= 0.0 ? r : -r;
}

// 8 ascending-k FMAs into one accumulator (order matches rounds 1-4)
#define DOT8(accv, WA, WB)                              \
    accv = fma((double)WA.x, h01.x, accv);              \
    accv = fma((double)WA.y, h01.y, accv);              \
    accv = fma((double)WA.z, h23.x, accv);              \
    accv = fma((double)WA.w, h23.y, accv);              \
    accv = fma((double)WB.x, h45.x, accv);              \
    accv = fma((double)WB.y, h45.y, accv);              \
    accv = fma((double)WB.z, h67.x, accv);              \
    accv = fma((double)WB.w, h67.y, accv);

// ---------- pre-pass: transpose weights into k-major float4 tiles ----------
__global__ void transpose_w(const float* __restrict__ W_ih,
                            const float* __restrict__ W_hh,
                            float4* __restrict__ wihT,
                            float4* __restrict__ whhT)
{
    int i = blockIdx.x * 256 + threadIdx.x;   // 1024 * 72 total
    if (i >= 1024 * 72) return;
    int gr = i / 72, s = i - gr * 72;
    if (s < 8) {
        const float* p = W_ih + (size_t)gr * Fsz + s * 4;
        wihT[s * 1024 + gr] = make_float4(p[0], p[1], p[2], p[3]);
    } else {
        int k4 = s - 8;
        const float* p = W_hh + (size_t)gr * Hsz + k4 * 4;
        whhT[k4 * 1024 + gr] = make_float4(p[0], p[1], p[2], p[3]);
    }
}

__global__ __launch_bounds__(NTHR, 2) void lstm_persist(
    const float* __restrict__ x,
    const float4* __restrict__ wihT, const float4* __restrict__ whhT,
    const float* __restrict__ b_ih, const float* __restrict__ b_hh,
    const float* __restrict__ W_fc, const float* __restrict__ b_fc,
    float* __restrict__ out)
{
    __shared__ __align__(16) double h_lds[RT][Hsz];     // 8 KB
    __shared__ __align__(16) double x_lds[RT][Fsz];     // 1 KB
    __shared__ double o_lds[RT][Osz];
    __shared__ float  wfc_lds[Osz * Hsz];               // 6 KB

    const int tid  = threadIdx.x;
    const int row0 = blockIdx.x * RT;
    const int j    = tid;                                // gate-channel owned

    for (int i = tid; i < RT * Hsz; i += NTHR) ((double*)h_lds)[i] = 0.0;
    for (int i = tid; i < Osz * Hsz; i += NTHR) wfc_lds[i] = W_fc[i];

    const double bias0 = (double)b_ih[0 * Hsz + j] + (double)b_hh[0 * Hsz + j];
    const double bias1 = (double)b_ih[1 * Hsz + j] + (double)b_hh[1 * Hsz + j];
    const double bias2 = (double)b_ih[2 * Hsz + j] + (double)b_hh[2 * Hsz + j];
    const double bias3 = (double)b_ih[3 * Hsz + j] + (double)b_hh[3 * Hsz + j];

    double c_reg[RT];
    #pragma unroll
    for (int r = 0; r < RT; ++r) c_reg[r] = 0.0;

    __syncthreads();

    for (int t = 0; t < NSTEP; ++t) {
        // ---- stage x[:, t (or t-Ssz), :]; fuse look-ahead o replacement ----
        if (tid < RT * Fsz) {
            int r = tid >> 5, f = tid & 31;
            int ts = (t < Ssz) ? t : (t - Ssz);
            double v;
            if (t >= Ssz && f < Osz) v = o_lds[r][f];
            else v = (double)x[((size_t)(row0 + r) * Ssz + ts) * Fsz + f];
            x_lds[r][f] = v;
        }
        __syncthreads();

        double acc[4][RT];
        #pragma unroll
        for (int r = 0; r < RT; ++r) {
            acc[0][r] = bias0; acc[1][r] = bias1; acc[2][r] = bias2; acc[3][r] = bias3;
        }

        // ---- F part: gates += W_ih . x  (coalesced k-major weight loads) ----
        #pragma unroll 1
        for (int k0 = 0; k0 < Fsz; k0 += 8) {
            const int s = k0 >> 2;
            float4 wa[4], wb[4];
            #pragma unroll
            for (int g = 0; g < 4; ++g) {
                wa[g] = wihT[(size_t)s * 1024 + (g << 8) + j];
                wb[g] = wihT[(size_t)(s + 1) * 1024 + (g << 8) + j];
            }
            #pragma unroll
            for (int r = 0; r < RT; ++r) {
                double2 h01 = *(const double2*)&x_lds[r][k0];
                double2 h23 = *(const double2*)&x_lds[r][k0 + 2];
                double2 h45 = *(const double2*)&x_lds[r][k0 + 4];
                double2 h67 = *(const double2*)&x_lds[r][k0 + 6];
                DOT8(acc[0][r], wa[0], wb[0]);
                DOT8(acc[1][r], wa[1], wb[1]);
                DOT8(acc[2][r], wa[2], wb[2]);
                DOT8(acc[3][r], wa[3], wb[3]);
            }
        }

        // ---- H part: gates += W_hh . h  (coalesced, next-chunk prefetch) ----
        {
            float4 wa[4], wb[4], na[4], nb[4];
            #pragma unroll
            for (int g = 0; g < 4; ++g) {
                wa[g] = whhT[(size_t)0 * 1024 + (g << 8) + j];
                wb[g] = whhT[(size_t)1 * 1024 + (g << 8) + j];
            }
            #pragma unroll 1
            for (int k0 = 0; k0 < Hsz; k0 += 8) {
                const int sn = (k0 + 8 < Hsz) ? ((k0 + 8) >> 2) : 0;
                #pragma unroll
                for (int g = 0; g < 4; ++g) {
                    na[g] = whhT[(size_t)sn * 1024 + (g << 8) + j];
                    nb[g] = whhT[(size_t)(sn + 1) * 1024 + (g << 8) + j];
                }
                #pragma unroll
                for (int r = 0; r < RT; ++r) {
                    double2 h01 = *(const double2*)&h_lds[r][k0];
                    double2 h23 = *(const double2*)&h_lds[r][k0 + 2];
                    double2 h45 = *(const double2*)&h_lds[r][k0 + 4];
                    double2 h67 = *(const double2*)&h_lds[r][k0 + 6];
                    DOT8(acc[0][r], wa[0], wb[0]);
                    DOT8(acc[1][r], wa[1], wb[1]);
                    DOT8(acc[2][r], wa[2], wb[2]);
                    DOT8(acc[3][r], wa[3], wb[3]);
                }
                #pragma unroll
                for (int g = 0; g < 4; ++g) { wa[g] = na[g]; wb[g] = nb[g]; }
            }
        }

        __syncthreads();   // all h_lds/x_lds reads complete before h update

        // ---- activations; update c (regs) and h (LDS) ----
        #pragma unroll
        for (int r = 0; r < RT; ++r) {
            double si = sigmoid_d(acc[0][r]);
            double sf = sigmoid_d(acc[1][r]);
            double tg = tanh_d(acc[2][r]);
            double so = sigmoid_d(acc[3][r]);
            double cn = fma(sf, c_reg[r], si * tg);
            c_reg[r] = cn;
            h_lds[r][j] = so * tanh_d(cn);
        }

        // ---- readout: wave w owns row w (RT=4 rows, 4 waves) ----
        if (t >= Ssz - 1) {
            __syncthreads();                              // h_lds complete
            const int w    = tid >> 6;                    // row 0..3
            const int lane = tid & 63;
            double a0 = 0.0, a1 = 0.0, a2 = 0.0, a3 = 0.0, a4 = 0.0, a5 = 0.0;
            #pragma unroll
            for (int m = 0; m < 4; ++m) {
                int k = lane + 64 * m;
                double hv = h_lds[w][k];
                bool b = hv > 0.0;
                a0 += b ? (double)wfc_lds[0 * Hsz + k] : 0.0;
                a1 += b ? (double)wfc_lds[1 * Hsz + k] : 0.0;
                a2 += b ? (double)wfc_lds[2 * Hsz + k] : 0.0;
                a3 += b ? (double)wfc_lds[3 * Hsz + k] : 0.0;
                a4 += b ? (double)wfc_lds[4 * Hsz + k] : 0.0;
                a5 += b ? (double)wfc_lds[5 * Hsz + k] : 0.0;
            }
            #pragma unroll
            for (int off = 32; off >= 1; off >>= 1) {
                a0 += __shfl_down(a0, off, 64);
                a1 += __shfl_down(a1, off, 64);
                a2 += __shfl_down(a2, off, 64);
                a3 += __shfl_down(a3, off, 64);
                a4 += __shfl_down(a4, off, 64);
                a5 += __shfl_down(a5, off, 64);
            }
            if (lane == 0) {
                size_t base = ((size_t)(row0 + w) * (LAsz + 1) + (t - (Ssz - 1))) * Osz;
                double o;
                o = (double)b_fc[0] + a0; o_lds[w][0] = o; out[base + 0] = (float)o;
                o = (double)b_fc[1] + a1; o_lds[w][1] = o; out[base + 1] = (float)o;
                o = (double)b_fc[2] + a2; o_lds[w][2] = o; out[base + 2] = (float)o;
                o = (double)b_fc[3] + a3; o_lds[w][3] = o; out[base + 3] = (float)o;
                o = (double)b_fc[4] + a4; o_lds[w][4] = o; out[base + 4] = (float)o;
                o = (double)b_fc[5] + a5; o_lds[w][5] = o; out[base + 5] = (float)o;
            }
            __syncthreads();                              // o_lds published
        }
        // non-readout steps: next iteration's stage barrier orders h writes vs reads
    }
}

extern "C" void kernel_launch(void* const* d_in, const int* in_sizes, int n_in,
                              void* d_out, int out_size, void* d_ws, size_t ws_size,
                              hipStream_t stream)
{
    const float* x    = (const float*)d_in[0];
    const float* W_ih = (const float*)d_in[1];
    const float* W_hh = (const float*)d_in[2];
    const float* b_ih = (const float*)d_in[3];
    const float* b_hh = (const float*)d_in[4];
    const float* W_fc = (const float*)d_in[5];
    const float* b_fc = (const float*)d_in[6];
    float* out = (float*)d_out;

    float4* whhT = (float4*)d_ws;                 // 64*1024 float4 = 1 MB
    float4* wihT = whhT + 64 * 1024;              // 8*1024 float4 = 128 KB

    transpose_w<<<dim3((1024 * 72 + 255) / 256), dim3(256), 0, stream>>>(
        W_ih, W_hh, wihT, whhT);

    lstm_persist<<<dim3(Bsz / RT), dim3(NTHR), 0, stream>>>(
        x, wihT, whhT, b_ih, b_hh, W_fc, b_fc, out);
}